// Round 2
// baseline (559.885 us; speedup 1.0000x reference)
//
#include <hip/hip_runtime.h>

// SVDAdapter: out = x @ (W + U*s*V^T)^T
// x: (8192,4096) f32, W: (4096,4096) f32, U: (4096,16), s: (16), V: (4096,16)
// Fast path: wh = f16(W + (U s) V^T) precomputed (32 MiB ws); x is read as f32
// DIRECTLY by the GEMM and converted to f16 in-register (same RNE rounding as
// the old xh prepass -> bit-identical MFMA inputs, absmax stays 8.0).
// GEMM: 256^2 tile, BK=64, 8 waves, 8-phase counted-vmcnt schedule.
//   A-side: T14 async-STAGE split - inline-asm global_load_dwordx4 issued at
//     P1/P3 (untracked by compiler waitcnt pass), cvt+ds_write_b128 at the
//     NEXT tile's P2/P4 under vmcnt(8); sched_barrier(0) after fences (rule 18).
//   B-side: global_load_lds from wh (unchanged, pre-swizzled source).
//   vmcnt ledger (per-thread VMEM issue order, steady state):
//     t.P1: A4(regs)  t.P2: B2(lds)  t.P3: A4  t.P4: B2
//     waits: P2 vmcnt(8) -> completes [t-1.P2:B2, t-1.P3:A4] (write A_k0(t+1))
//            P4 vmcnt(8) -> completes [t.P1:A4 and older]    (write A_k1(t+1))
//     prologue leaves exactly [B_k0(1):2, A_k0(1):4, B_k1(1):2] = 8 in flight.
// Fallback (ws too small): fp32 VALU GEMM + rank-16 fixup (unchanged).

#define IN_F   4096
#define OUT_F  4096
#define RANK   16
#define M_ROWS 8192
#define BM 256
#define BN 256
#define BK 64
#define NT (IN_F / BK)   // 64 K-tiles

typedef _Float16 f16x8 __attribute__((ext_vector_type(8)));
typedef _Float16 f16x4 __attribute__((ext_vector_type(4)));
typedef float    f32x4 __attribute__((ext_vector_type(4)));

// ---------------------------------------------------------------- async copy
__device__ __forceinline__ void async16(const void* gp, void* lp) {
  __builtin_amdgcn_global_load_lds(
      (const __attribute__((address_space(1))) void*)gp,
      (__attribute__((address_space(3))) void*)lp, 16, 0, 0);
}

// untracked global load: compiler's waitcnt pass can't see it, so it cannot
// insert a tight vmcnt stall at the use site; we order with manual fences.
__device__ __forceinline__ f32x4 gload(const float* p) {
  f32x4 r;
  asm volatile("global_load_dwordx4 %0, %1, off" : "=v"(r) : "v"(p));
  return r;
}

// ---------------------------------------------------------------- prep W
// wh[o][i] = f16( W[o][i] + sum_r U[o][r]*s[r]*V[i][r] )
__global__ __launch_bounds__(256)
void prep_w_kernel(const float* __restrict__ W,
                   const float* __restrict__ U,
                   const float* __restrict__ S,
                   const float* __restrict__ V,
                   _Float16* __restrict__ wh) {
  int t = blockIdx.x * 256 + threadIdx.x;   // < 1024*512
  int i4 = (t & 1023) << 2;                 // i column group
  int o0 = (t >> 10) << 3;                  // 8 o-rows per thread

  float v[4][RANK];
#pragma unroll
  for (int j = 0; j < 4; ++j) {
    const float4* vp = (const float4*)(V + (size_t)(i4 + j) * RANK);
#pragma unroll
    for (int q = 0; q < 4; ++q) {
      float4 vv = vp[q];
      v[j][q * 4 + 0] = vv.x; v[j][q * 4 + 1] = vv.y;
      v[j][q * 4 + 2] = vv.z; v[j][q * 4 + 3] = vv.w;
    }
  }
  float sv[RANK];
#pragma unroll
  for (int r = 0; r < RANK; r += 4) {
    float4 ss = *(const float4*)(S + r);
    sv[r] = ss.x; sv[r + 1] = ss.y; sv[r + 2] = ss.z; sv[r + 3] = ss.w;
  }

  for (int oo = 0; oo < 8; ++oo) {
    int o = o0 + oo;
    float us[RANK];
    const float4* up = (const float4*)(U + (size_t)o * RANK);
#pragma unroll
    for (int r = 0; r < RANK; r += 4) {
      float4 uu = up[r >> 2];
      us[r] = uu.x * sv[r]; us[r + 1] = uu.y * sv[r + 1];
      us[r + 2] = uu.z * sv[r + 2]; us[r + 3] = uu.w * sv[r + 3];
    }
    float4 w = *(const float4*)(W + (size_t)o * IN_F + i4);
    float d0 = w.x, d1 = w.y, d2 = w.z, d3 = w.w;
#pragma unroll
    for (int r = 0; r < RANK; ++r) {
      d0 += us[r] * v[0][r];
      d1 += us[r] * v[1][r];
      d2 += us[r] * v[2][r];
      d3 += us[r] * v[3][r];
    }
    f16x4 h;
    h[0] = (_Float16)d0; h[1] = (_Float16)d1;
    h[2] = (_Float16)d2; h[3] = (_Float16)d3;
    *(f16x4*)(wh + (size_t)o * IN_F + i4) = h;
  }
}

// ---------------------------------------------------------------- GEMM (fast)
// out[m][o] = sum_k f16(x[m][k]) * wh[o][k]   ("NT": both operands K-major)
// LDS: 8 regions of 16 KiB (256 rows x 64B):
//   buf p @ p*65536:  A_k0 +0, B_k0 +16384, A_k1 +32768, B_k1 +49152
// Rows = 4 chunks of 16B; stored chunk c holds data chunk c ^ ((r>>1)&3)
// (swizzle applied on the GLOBAL gather for both the B-side global_load_lds
// source and the A-side f32 register loads; LDS dest/write stays linear).
__global__ __launch_bounds__(512, 2)
void gemm_kernel(const float* __restrict__ x,
                 const _Float16* __restrict__ wh,
                 float* __restrict__ out) {
  __shared__ unsigned char lds[131072];

  // bijective XCD swizzle (512 blocks % 8 == 0)
  const int orig = blockIdx.x;
  const int wg = (orig & 7) * 64 + (orig >> 3);
  const int mt = wg >> 4;          // 0..31
  const int nt = wg & 15;          // 0..15 fastest -> neighbors share A panel
  const int blockM = mt * BM;
  const int blockN = nt * BN;

  const int tid = threadIdx.x;
  const int lane = tid & 63;
  const int wave = tid >> 6;       // 0..7
  const int wm = wave >> 2;        // 0..1
  const int wn = wave & 3;         // 0..3

  // ---- staging addresses: one half-tile = 256 rows x 32 elems = 1024 chunks,
  //      512 threads x 2 slots; LDS dest linear in slot.
  const float*    aSrc0;           // slot tid      (f32 source, swizzled chunk)
  const float*    aSrc1;           // slot tid+512
  const _Float16* bSrc[2];
  unsigned ldsOff0, ldsOff1;
  {
    int slot = tid;
    int r = slot >> 2, c = slot & 3, cd = c ^ ((r >> 1) & 3);
    aSrc0 = x + (size_t)(blockM + r) * IN_F + cd * 8;
    bSrc[0] = wh + (size_t)(blockN + r) * IN_F + cd * 8;
    ldsOff0 = (unsigned)slot * 16;
    slot = tid + 512;
    r = slot >> 2; c = slot & 3; cd = c ^ ((r >> 1) & 3);
    aSrc1 = x + (size_t)(blockM + r) * IN_F + cd * 8;
    bSrc[1] = wh + (size_t)(blockN + r) * IN_F + cd * 8;
    ldsOff1 = (unsigned)slot * 16;
  }

  // ---- fragment LDS offsets within a region (iter-invariant)
  const int kg = lane >> 4;
  unsigned offA[4], offB[4];
#pragma unroll
  for (int t = 0; t < 4; ++t) {
    int ar = wm * 128 + t * 16 + (lane & 15);
    offA[t] = (unsigned)(ar * 64 + ((kg ^ ((ar >> 1) & 3)) * 16));
    int br = wn * 64 + t * 16 + (lane & 15);
    offB[t] = (unsigned)(br * 64 + ((kg ^ ((br >> 1) & 3)) * 16));
  }

  f32x4 acc[8][4];
#pragma unroll
  for (int i = 0; i < 8; ++i)
#pragma unroll
    for (int j = 0; j < 4; ++j) acc[i][j] = (f32x4){0.f, 0.f, 0.f, 0.f};

  // A-staging register sets (static names only - rule #20)
  f32x4 s0a = {0,0,0,0}, s0b = {0,0,0,0}, s0c = {0,0,0,0}, s0d = {0,0,0,0};
  f32x4 s1a = {0,0,0,0}, s1b = {0,0,0,0}, s1c = {0,0,0,0}, s1d = {0,0,0,0};

#define STG(LDSBASE, KOFS)                                           \
  {                                                                  \
    async16(bSrc[0] + (KOFS), lds + (LDSBASE) + ldsOff0);            \
    async16(bSrc[1] + (KOFS), lds + (LDSBASE) + ldsOff1);            \
  }

// convert 16 f32 (4x f32x4: P,Q = slot0; R,S = slot1) -> f16, write 2x b128
#define CVTW(REGOFF, P, Q, R, S)                                     \
  {                                                                  \
    f16x8 h0, h1;                                                    \
    h0[0] = (_Float16)(P)[0]; h0[1] = (_Float16)(P)[1];              \
    h0[2] = (_Float16)(P)[2]; h0[3] = (_Float16)(P)[3];              \
    h0[4] = (_Float16)(Q)[0]; h0[5] = (_Float16)(Q)[1];              \
    h0[6] = (_Float16)(Q)[2]; h0[7] = (_Float16)(Q)[3];              \
    h1[0] = (_Float16)(R)[0]; h1[1] = (_Float16)(R)[1];              \
    h1[2] = (_Float16)(R)[2]; h1[3] = (_Float16)(R)[3];              \
    h1[4] = (_Float16)(S)[0]; h1[5] = (_Float16)(S)[1];              \
    h1[6] = (_Float16)(S)[2]; h1[7] = (_Float16)(S)[3];              \
    *(f16x8*)(lds + (REGOFF) + ldsOff0) = h0;                        \
    *(f16x8*)(lds + (REGOFF) + ldsOff1) = h1;                        \
  }

  // ---- prologue -----------------------------------------------------------
  // A(0) both k-halves via plain C loads (compiler-tracked, fully drained
  // before any untracked VMEM is issued).
  {
    f32x4 p0 = *(const f32x4*)(aSrc0 + 0);
    f32x4 p1 = *(const f32x4*)(aSrc0 + 4);
    f32x4 p2 = *(const f32x4*)(aSrc1 + 0);
    f32x4 p3 = *(const f32x4*)(aSrc1 + 4);
    f32x4 q0 = *(const f32x4*)(aSrc0 + 32);
    f32x4 q1 = *(const f32x4*)(aSrc0 + 36);
    f32x4 q2 = *(const f32x4*)(aSrc1 + 32);
    f32x4 q3 = *(const f32x4*)(aSrc1 + 36);
    CVTW(0,     p0, p1, p2, p3);          // A_k0(0) -> buf0
    CVTW(32768, q0, q1, q2, q3);          // A_k1(0) -> buf0
    asm volatile("s_waitcnt vmcnt(0)" ::: "memory");  // clean VMEM slate
  }
  // untracked VMEM, exact steady-state issue order:
  STG(16384, 0);                  // B_k0(0)   [2]
  STG(49152, 32);                 // B_k1(0)   [2]
  STG(65536 + 16384, 64);         // B_k0(1)   [2]  (mimics t-1.P2)
  s1a = gload(aSrc0 + 64); s1b = gload(aSrc0 + 68);   // A_k0(1) [4] (t-1.P3)
  s1c = gload(aSrc1 + 64); s1d = gload(aSrc1 + 68);
  STG(65536 + 49152, 96);         // B_k1(1)   [2]  (mimics t-1.P4)
  asm volatile("s_waitcnt vmcnt(8)" ::: "memory");    // B(0) resident
  asm volatile("s_waitcnt lgkmcnt(0)" ::: "memory");  // A(0) writes landed
  __builtin_amdgcn_s_barrier();

  const float* aP0 = aSrc0;
  const float* aP1 = aSrc1;

#pragma unroll 2
  for (int t = 0; t < NT; ++t) {
    const unsigned base = (unsigned)(t & 1) << 16;
    const unsigned baseN = base ^ 65536u;
    const int kof2 = (t + 2) * BK;
    const bool ok1 = (t + 1) < NT;
    const bool ok2 = (t + 2) < NT;

    f16x8 aF[4], bF[4];

    // ---------------- P1: (mh=0, k0); issue A_k1(t+1) loads -> set0 --------
#pragma unroll
    for (int i = 0; i < 4; ++i)
      aF[i] = *(const f16x8*)(lds + base + offA[i]);
#pragma unroll
    for (int j = 0; j < 4; ++j)
      bF[j] = *(const f16x8*)(lds + base + 16384 + offB[j]);
    if (ok1) {
      s0a = gload(aP0 + 96);  s0b = gload(aP0 + 100);
      s0c = gload(aP1 + 96);  s0d = gload(aP1 + 100);
    }
    __builtin_amdgcn_s_barrier();
    asm volatile("s_waitcnt lgkmcnt(0)" ::: "memory");
    __builtin_amdgcn_sched_barrier(0);
    __builtin_amdgcn_s_setprio(1);
#pragma unroll
    for (int i = 0; i < 4; ++i)
#pragma unroll
      for (int j = 0; j < 4; ++j)
        acc[i][j] = __builtin_amdgcn_mfma_f32_16x16x32_f16(aF[i], bF[j], acc[i][j], 0, 0, 0);
    __builtin_amdgcn_s_setprio(0);
    __builtin_amdgcn_s_barrier();

    // ---------------- P2: (mh=1, k0); stage B_k0(t+2); write set1 ----------
#pragma unroll
    for (int i = 0; i < 4; ++i)
      aF[i] = *(const f16x8*)(lds + base + 4096 + offA[i]);
    if (ok2) STG(base + 16384, kof2);
    if (ok2) { asm volatile("s_waitcnt vmcnt(8)" ::: "memory"); }
    else     { asm volatile("s_waitcnt vmcnt(0)" ::: "memory"); }
    __builtin_amdgcn_sched_barrier(0);
    if (ok1) CVTW(baseN + 0, s1a, s1b, s1c, s1d);     // A_k0(t+1)
    __builtin_amdgcn_s_barrier();
    asm volatile("s_waitcnt lgkmcnt(0)" ::: "memory");
    __builtin_amdgcn_sched_barrier(0);
    __builtin_amdgcn_s_setprio(1);
#pragma unroll
    for (int i = 0; i < 4; ++i)
#pragma unroll
      for (int j = 0; j < 4; ++j)
        acc[4 + i][j] = __builtin_amdgcn_mfma_f32_16x16x32_f16(aF[i], bF[j], acc[4 + i][j], 0, 0, 0);
    __builtin_amdgcn_s_setprio(0);
    __builtin_amdgcn_s_barrier();

    // ---------------- P3: (mh=0, k1); issue A_k0(t+2) loads -> set1 --------
#pragma unroll
    for (int i = 0; i < 4; ++i)
      aF[i] = *(const f16x8*)(lds + base + 32768 + offA[i]);
#pragma unroll
    for (int j = 0; j < 4; ++j)
      bF[j] = *(const f16x8*)(lds + base + 49152 + offB[j]);
    if (ok2) {
      s1a = gload(aP0 + 128); s1b = gload(aP0 + 132);
      s1c = gload(aP1 + 128); s1d = gload(aP1 + 132);
    }
    __builtin_amdgcn_s_barrier();
    asm volatile("s_waitcnt lgkmcnt(0)" ::: "memory");
    __builtin_amdgcn_sched_barrier(0);
    __builtin_amdgcn_s_setprio(1);
#pragma unroll
    for (int i = 0; i < 4; ++i)
#pragma unroll
      for (int j = 0; j < 4; ++j)
        acc[i][j] = __builtin_amdgcn_mfma_f32_16x16x32_f16(aF[i], bF[j], acc[i][j], 0, 0, 0);
    __builtin_amdgcn_s_setprio(0);
    __builtin_amdgcn_s_barrier();

    // ---------------- P4: (mh=1, k1); stage B_k1(t+2); write set0 ----------
#pragma unroll
    for (int i = 0; i < 4; ++i)
      aF[i] = *(const f16x8*)(lds + base + 32768 + 4096 + offA[i]);
    if (ok2) STG(base + 49152, kof2 + 32);
    if (ok2) { asm volatile("s_waitcnt vmcnt(8)" ::: "memory"); }
    else     { asm volatile("s_waitcnt vmcnt(0)" ::: "memory"); }
    __builtin_amdgcn_sched_barrier(0);
    if (ok1) CVTW(baseN + 32768, s0a, s0b, s0c, s0d); // A_k1(t+1)
    __builtin_amdgcn_s_barrier();
    asm volatile("s_waitcnt lgkmcnt(0)" ::: "memory");
    __builtin_amdgcn_sched_barrier(0);
    __builtin_amdgcn_s_setprio(1);
#pragma unroll
    for (int i = 0; i < 4; ++i)
#pragma unroll
      for (int j = 0; j < 4; ++j)
        acc[4 + i][j] = __builtin_amdgcn_mfma_f32_16x16x32_f16(aF[i], bF[j], acc[4 + i][j], 0, 0, 0);
    __builtin_amdgcn_s_setprio(0);
    __builtin_amdgcn_s_barrier();

    aP0 += BK; aP1 += BK;
  }
#undef STG
#undef CVTW

  // C/D layout col=lane&15, row=(lane>>4)*4+reg  [measured m89/m91]
  const int col0 = blockN + wn * 64 + (lane & 15);
  const int row0 = blockM + wm * 128 + (lane >> 4) * 4;
#pragma unroll
  for (int i = 0; i < 8; ++i)
#pragma unroll
    for (int j = 0; j < 4; ++j) {
      float* op = out + (size_t)(row0 + i * 16) * OUT_F + col0 + j * 16;
#pragma unroll
      for (int rr = 0; rr < 4; ++rr) op[(size_t)rr * OUT_F] = acc[i][j][rr];
    }
}

// ================================================================ FALLBACK
// fp32 VALU GEMM out = x @ W^T (64x64 tile), then out += (x V s) U^T.
__global__ __launch_bounds__(256)
void fb_gemm(const float* __restrict__ x, const float* __restrict__ W,
             float* __restrict__ out) {
  __shared__ float xs[64][17];
  __shared__ float wsm[64][17];
  const int mt = blockIdx.x >> 6;
  const int ntile = blockIdx.x & 63;
  const int bM = mt * 64, bN = ntile * 64;
  const int t = threadIdx.x;
  const int lr = t >> 2, lc = (t & 3) * 4;
  const int tm = t >> 4, tn = t & 15;

  float acc[4][4];
#pragma unroll
  for (int i = 0; i < 4; ++i)
#pragma unroll
    for (int j = 0; j < 4; ++j) acc[i][j] = 0.f;

  for (int kk = 0; kk < IN_F; kk += 16) {
    float4 xa = *(const float4*)(x + (size_t)(bM + lr) * IN_F + kk + lc);
    float4 wa = *(const float4*)(W + (size_t)(bN + lr) * IN_F + kk + lc);
    xs[lr][lc + 0] = xa.x; xs[lr][lc + 1] = xa.y;
    xs[lr][lc + 2] = xa.z; xs[lr][lc + 3] = xa.w;
    wsm[lr][lc + 0] = wa.x; wsm[lr][lc + 1] = wa.y;
    wsm[lr][lc + 2] = wa.z; wsm[lr][lc + 3] = wa.w;
    __syncthreads();
#pragma unroll
    for (int k = 0; k < 16; ++k) {
      float a[4], b[4];
#pragma unroll
      for (int i = 0; i < 4; ++i) a[i] = xs[tm * 4 + i][k];
#pragma unroll
      for (int j = 0; j < 4; ++j) b[j] = wsm[tn * 4 + j][k];
#pragma unroll
      for (int i = 0; i < 4; ++i)
#pragma unroll
        for (int j = 0; j < 4; ++j) acc[i][j] += a[i] * b[j];
    }
    __syncthreads();
  }
#pragma unroll
  for (int i = 0; i < 4; ++i)
#pragma unroll
    for (int j = 0; j < 4; ++j)
      out[(size_t)(bM + tm * 4 + i) * OUT_F + bN + tn * 4 + j] = acc[i][j];
}

__global__ void fb_xv(const float* __restrict__ x, const float* __restrict__ V,
                      const float* __restrict__ S, float* __restrict__ xv) {
  int m = blockIdx.x * 4 + (threadIdx.x >> 6);
  int lane = threadIdx.x & 63;
  float a[RANK];
#pragma unroll
  for (int r = 0; r < RANK; ++r) a[r] = 0.f;
  for (int k = lane; k < IN_F; k += 64) {
    float xe = x[(size_t)m * IN_F + k];
    const float4* vp = (const float4*)(V + (size_t)k * RANK);
#pragma unroll
    for (int q = 0; q < 4; ++q) {
      float4 vv = vp[q];
      a[q * 4 + 0] += xe * vv.x; a[q * 4 + 1] += xe * vv.y;
      a[q * 4 + 2] += xe * vv.z; a[q * 4 + 3] += xe * vv.w;
    }
  }
#pragma unroll
  for (int r = 0; r < RANK; ++r)
    for (int off = 32; off; off >>= 1) a[r] += __shfl_down(a[r], off);
  if (lane == 0) {
#pragma unroll
    for (int r = 0; r < RANK; ++r) xv[(size_t)m * RANK + r] = a[r] * S[r];
  }
}

__global__ void fb_add(const float* __restrict__ xv, const float* __restrict__ U,
                       float* __restrict__ out) {
  size_t t = (size_t)blockIdx.x * 256 + threadIdx.x;
  int m = (int)(t >> 12), o = (int)(t & 4095);
  const float* xr = xv + (size_t)m * RANK;
  const float* ur = U + (size_t)o * RANK;
  float d = 0.f;
#pragma unroll
  for (int r = 0; r < RANK; ++r) d += xr[r] * ur[r];
  out[t] += d;
}

// ---------------------------------------------------------------- launch
extern "C" void kernel_launch(void* const* d_in, const int* in_sizes, int n_in,
                              void* d_out, int out_size, void* d_ws, size_t ws_size,
                              hipStream_t stream) {
  const float* x = (const float*)d_in[0];
  const float* W = (const float*)d_in[1];
  const float* U = (const float*)d_in[2];
  const float* s = (const float*)d_in[3];
  const float* V = (const float*)d_in[4];
  float* out = (float*)d_out;

  // workspace: wh (4096*4096 f16) = 32 MiB
  const size_t need = (size_t)OUT_F * IN_F * 2;
  if (ws_size >= need) {
    _Float16* wh = (_Float16*)d_ws;
    prep_w_kernel<<<((IN_F / 4) * (OUT_F / 8)) / 256, 256, 0, stream>>>(W, U, s, V, wh);
    gemm_kernel<<<(M_ROWS / BM) * (OUT_F / BN), 512, 0, stream>>>(x, wh, out);
  } else {
    float* xv = (float*)d_ws;  // 8192*16 f32 = 512 KiB
    fb_gemm<<<(M_ROWS / 64) * (OUT_F / 64), 256, 0, stream>>>(x, W, out);
    fb_xv<<<M_ROWS / 4, 256, 0, stream>>>(x, V, s, xv);
    fb_add<<<(size_t)M_ROWS * OUT_F / 256, 256, 0, stream>>>(xv, U, out);
  }
}

// Round 3
// 537.932 us; speedup vs baseline: 1.0408x; 1.0408x over previous
//
#include <hip/hip_runtime.h>

// SVDAdapter: out = x @ (W + U*s*V^T)^T
// x: (8192,4096) f32, W: (4096,4096) f32, U: (4096,16), s: (16), V: (4096,16)
// Fast path (R1 structure + counted-lgkm register pipeline):
//   prep (1 dispatch): x -> xh f16  ||  wh = f16(W + (U s) V^T)
//   gemm: 256^2 tile, BK=64, 8 waves, 4 phases/K-tile, ONE barrier per phase.
//     Fragment ds_reads for phase p+1 issue right after phase p's barrier;
//     wait is counted lgkmcnt(N_issued_this_phase) -> completes phase p's
//     fragments while p+1's stay in flight (read latency hidden under MFMA).
//     B/A staged via global_load_lds, pre-swizzled source (chunk ^ (r>>1)&3).
//     One vmcnt(4) per K-tile at P4 (pre-barrier) covers buf(t+1) residency.
//     Hazard ledger (verified): every region has >=2 barriers + a counted
//     lgkm wait between last read-issue and overwrite; last 2 tiles peeled
//     with vmcnt(0) drains. Numerics identical to 617us kernel (absmax 8.0).
// Fallback (ws too small): fp32 VALU GEMM + rank-16 fixup (unchanged).

#define IN_F   4096
#define OUT_F  4096
#define RANK   16
#define M_ROWS 8192
#define BM 256
#define BN 256
#define BK 64
#define NT (IN_F / BK)   // 64 K-tiles

typedef _Float16 f16x8 __attribute__((ext_vector_type(8)));
typedef _Float16 f16x4 __attribute__((ext_vector_type(4)));
typedef float    f32x4 __attribute__((ext_vector_type(4)));

// ---------------------------------------------------------------- async copy
__device__ __forceinline__ void async16(const void* gp, void* lp) {
  __builtin_amdgcn_global_load_lds(
      (const __attribute__((address_space(1))) void*)gp,
      (__attribute__((address_space(3))) void*)lp, 16, 0, 0);
}

// ---------------------------------------------------------------- fused prep
// blocks [0, 4096):   x (f32) -> xh (f16), grid-stride, 8 float4 per thread
// blocks [4096, 6144): wh[o][i] = f16( W[o][i] + sum_r U[o][r]*s[r]*V[i][r] )
#define SPLIT_BLOCKS 4096

__global__ __launch_bounds__(256)
void prep_kernel(const float* __restrict__ x, _Float16* __restrict__ xh,
                 const float* __restrict__ W, const float* __restrict__ U,
                 const float* __restrict__ S, const float* __restrict__ V,
                 _Float16* __restrict__ wh) {
  if (blockIdx.x < SPLIT_BLOCKS) {
    size_t t = (size_t)blockIdx.x * 256 + threadIdx.x;
#pragma unroll
    for (int it = 0; it < 8; ++it) {   // 8192*4096/4 / (4096*256) = 8
      float4 v = ((const float4*)x)[t];
      f16x4 h;
      h[0] = (_Float16)v.x; h[1] = (_Float16)v.y;
      h[2] = (_Float16)v.z; h[3] = (_Float16)v.w;
      ((f16x4*)xh)[t] = h;
      t += (size_t)SPLIT_BLOCKS * 256;
    }
  } else {
    int t = (int)(blockIdx.x - SPLIT_BLOCKS) * 256 + threadIdx.x;  // < 1024*512
    int i4 = (t & 1023) << 2;                 // i column group
    int o0 = (t >> 10) << 3;                  // 8 o-rows per thread

    float v[4][RANK];
#pragma unroll
    for (int j = 0; j < 4; ++j) {
      const float4* vp = (const float4*)(V + (size_t)(i4 + j) * RANK);
#pragma unroll
      for (int q = 0; q < 4; ++q) {
        float4 vv = vp[q];
        v[j][q * 4 + 0] = vv.x; v[j][q * 4 + 1] = vv.y;
        v[j][q * 4 + 2] = vv.z; v[j][q * 4 + 3] = vv.w;
      }
    }
    float sv[RANK];
#pragma unroll
    for (int r = 0; r < RANK; r += 4) {
      float4 ss = *(const float4*)(S + r);
      sv[r] = ss.x; sv[r + 1] = ss.y; sv[r + 2] = ss.z; sv[r + 3] = ss.w;
    }

    for (int oo = 0; oo < 8; ++oo) {
      int o = o0 + oo;
      float us[RANK];
      const float4* up = (const float4*)(U + (size_t)o * RANK);
#pragma unroll
      for (int r = 0; r < RANK; r += 4) {
        float4 uu = up[r >> 2];
        us[r] = uu.x * sv[r]; us[r + 1] = uu.y * sv[r + 1];
        us[r + 2] = uu.z * sv[r + 2]; us[r + 3] = uu.w * sv[r + 3];
      }
      float4 w = *(const float4*)(W + (size_t)o * IN_F + i4);
      float d0 = w.x, d1 = w.y, d2 = w.z, d3 = w.w;
#pragma unroll
      for (int r = 0; r < RANK; ++r) {
        d0 += us[r] * v[0][r];
        d1 += us[r] * v[1][r];
        d2 += us[r] * v[2][r];
        d3 += us[r] * v[3][r];
      }
      f16x4 h;
      h[0] = (_Float16)d0; h[1] = (_Float16)d1;
      h[2] = (_Float16)d2; h[3] = (_Float16)d3;
      *(f16x4*)(wh + (size_t)o * IN_F + i4) = h;
    }
  }
}

// ---------------------------------------------------------------- GEMM (fast)
// out[m][o] = sum_k xh[m][k]*wh[o][k]  ("NT": both operands K-major)
// LDS: 8 regions of 16 KiB (256 rows x 64B):
//   buf p @ p*65536:  A_k0 +0, B_k0 +16384, A_k1 +32768, B_k1 +49152
// Rows = 4 chunks of 16B; stored chunk c holds data chunk c ^ ((r>>1)&3)
// (swizzle applied on the GLOBAL gather; LDS dest stays linear).
//
// Phase schedule (1 barrier/phase, counted lgkm; per-tile staging rotation):
//   P1: bar; rd aFB(mh1,k0)[4];       STG A_k1(t+1);       lgkm(4); MFMA lo (aFA,bF0)
//   P2: bar; rd aFA(mh0,k1)[4]+bF1[4];STG B_k0(t+2);       lgkm(8); MFMA hi (aFB,bF0)
//   P3: bar; rd aFB(mh1,k1)[4];       STG A_k0(t+2);       lgkm(4); MFMA lo (aFA,bF1)
//   P4: vmcnt(4); bar; rd aFA(t+1)[4]+bF0(t+1)[4]; STG B_k1(t+2); lgkm(8); MFMA hi
__global__ __launch_bounds__(512, 2)
void gemm_kernel(const _Float16* __restrict__ xh,
                 const _Float16* __restrict__ wh,
                 float* __restrict__ out) {
  __shared__ unsigned char lds[131072];

  // bijective XCD swizzle (512 blocks % 8 == 0)
  const int orig = blockIdx.x;
  const int wg = (orig & 7) * 64 + (orig >> 3);
  const int mt = wg >> 4;          // 0..31
  const int nt = wg & 15;          // 0..15 fastest -> neighbors share A panel
  const int blockM = mt * BM;
  const int blockN = nt * BN;

  const int tid = threadIdx.x;
  const int lane = tid & 63;
  const int wave = tid >> 6;       // 0..7
  const int wm = wave >> 2;        // 0..1
  const int wn = wave & 3;         // 0..3

  // ---- staging addresses: one half-tile = 256 rows x 32 f16 = 1024 chunks,
  //      512 threads x 2 slots; LDS dest linear in slot.
  const _Float16* aSrc[2];
  const _Float16* bSrc[2];
  unsigned ldsOff[2];
#pragma unroll
  for (int q = 0; q < 2; ++q) {
    int slot = q * 512 + tid;           // 0..1023
    int r = slot >> 2;                  // region row 0..255
    int c = slot & 3;                   // stored chunk
    int cd = c ^ ((r >> 1) & 3);        // data chunk (swizzle on the gather)
    aSrc[q] = xh + (size_t)(blockM + r) * IN_F + cd * 8;
    bSrc[q] = wh + (size_t)(blockN + r) * IN_F + cd * 8;
    ldsOff[q] = (unsigned)slot * 16;
  }

  // ---- fragment LDS offsets within a region (iter-invariant)
  const int kg = lane >> 4;
  unsigned offA[4], offB[4];
#pragma unroll
  for (int t = 0; t < 4; ++t) {
    int ar = wm * 128 + t * 16 + (lane & 15);   // mh0 rows; mh1 = +64 rows (+4096B)
    offA[t] = (unsigned)(ar * 64 + ((kg ^ ((ar >> 1) & 3)) * 16));
    int br = wn * 64 + t * 16 + (lane & 15);
    offB[t] = (unsigned)(br * 64 + ((kg ^ ((br >> 1) & 3)) * 16));
  }

  f32x4 acc[8][4];
#pragma unroll
  for (int i = 0; i < 8; ++i)
#pragma unroll
    for (int j = 0; j < 4; ++j) acc[i][j] = (f32x4){0.f, 0.f, 0.f, 0.f};

  f16x8 aFA[4], aFB[4], bF0[4], bF1[4];

#define STG(SRC, LDSBASE, KOFS)                                      \
  {                                                                  \
    async16(SRC[0] + (KOFS), lds + (LDSBASE) + ldsOff[0]);           \
    async16(SRC[1] + (KOFS), lds + (LDSBASE) + ldsOff[1]);           \
  }
#define RD4(DST, RB, OFF)                                            \
  {                                                                  \
    DST[0] = *(const f16x8*)(lds + (RB) + OFF[0]);                   \
    DST[1] = *(const f16x8*)(lds + (RB) + OFF[1]);                   \
    DST[2] = *(const f16x8*)(lds + (RB) + OFF[2]);                   \
    DST[3] = *(const f16x8*)(lds + (RB) + OFF[3]);                   \
  }
#define PH_BAR() asm volatile("s_barrier" ::: "memory")
#define WAITL(N) asm volatile("s_waitcnt lgkmcnt(" #N ")" ::: "memory")
#define WAITV(N) asm volatile("s_waitcnt vmcnt(" #N ")" ::: "memory")
#define MFMA16(AO, A, B)                                             \
  {                                                                  \
    __builtin_amdgcn_sched_barrier(0);                               \
    __builtin_amdgcn_s_setprio(1);                                   \
    _Pragma("unroll")                                                \
    for (int i_ = 0; i_ < 4; ++i_) {                                 \
      _Pragma("unroll")                                              \
      for (int j_ = 0; j_ < 4; ++j_)                                 \
        acc[(AO) + i_][j_] = __builtin_amdgcn_mfma_f32_16x16x32_f16( \
            (A)[i_], (B)[j_], acc[(AO) + i_][j_], 0, 0, 0);          \
    }                                                                \
    __builtin_amdgcn_s_setprio(0);                                   \
  }

  // ---- prologue: buf0 full + buf1 {B_k0, A_k0, B_k1}; 6 loads stay in flight.
  STG(aSrc, 0, 0);                 // A_k0(0)
  STG(bSrc, 16384, 0);             // B_k0(0)
  STG(aSrc, 32768, 32);            // A_k1(0)
  STG(bSrc, 49152, 32);            // B_k1(0)
  STG(bSrc, 65536 + 16384, 64);    // B_k0(1)   (plays t-1.P2)
  STG(aSrc, 65536 + 0, 64);        // A_k0(1)   (plays t-1.P3)
  STG(bSrc, 65536 + 49152, 96);    // B_k1(1)   (plays t-1.P4)
  WAITV(6);                        // buf0 resident
  PH_BAR();
  RD4(aFA, 0, offA);               // buf0 A_k0 mh0   (plays t-1.P4's reads)
  RD4(bF0, 16384, offB);           // buf0 B_k0

  // ---- main loop: t = 0 .. NT-3 (no boundary branches)
#pragma unroll 2
  for (int t = 0; t < NT - 2; ++t) {
    const unsigned base  = (unsigned)(t & 1) << 16;
    const unsigned baseN = base ^ 65536u;
    const int kof1 = (t + 1) * BK;
    const int kof2 = (t + 2) * BK;

    // P1
    PH_BAR();
    RD4(aFB, base + 4096, offA);
    STG(aSrc, baseN + 32768, kof1 + 32);    // A_k1(t+1)
    WAITL(4);
    MFMA16(0, aFA, bF0);

    // P2
    PH_BAR();
    RD4(aFA, base + 32768, offA);
    RD4(bF1, base + 49152, offB);
    STG(bSrc, base + 16384, kof2);          // B_k0(t+2)
    WAITL(8);
    MFMA16(4, aFB, bF0);

    // P3
    PH_BAR();
    RD4(aFB, base + 32768 + 4096, offA);
    STG(aSrc, base + 0, kof2);              // A_k0(t+2)
    WAITL(4);
    MFMA16(0, aFA, bF1);

    // P4
    WAITV(4);                               // buf(t+1) fully resident
    PH_BAR();
    RD4(aFA, baseN + 0, offA);
    RD4(bF0, baseN + 16384, offB);
    STG(bSrc, base + 49152, kof2 + 32);     // B_k1(t+2)
    WAITL(8);
    MFMA16(4, aFB, bF1);
  }

  // ---- peeled tile NT-2 (base=0, baseN=65536): only A_k1(NT-1) staged
  {
    const unsigned base = 0, baseN = 65536u;
    const int kof1 = (NT - 1) * BK;
    PH_BAR();
    RD4(aFB, base + 4096, offA);
    STG(aSrc, baseN + 32768, kof1 + 32);    // A_k1(NT-1)
    WAITL(4);
    MFMA16(0, aFA, bF0);

    PH_BAR();
    RD4(aFA, base + 32768, offA);
    RD4(bF1, base + 49152, offB);
    WAITL(8);
    MFMA16(4, aFB, bF0);

    PH_BAR();
    RD4(aFB, base + 32768 + 4096, offA);
    WAITL(4);
    MFMA16(0, aFA, bF1);

    WAITV(0);                               // drain: buf(NT-1) fully resident
    PH_BAR();
    RD4(aFA, baseN + 0, offA);
    RD4(bF0, baseN + 16384, offB);
    WAITL(8);
    MFMA16(4, aFB, bF1);
  }
  // ---- peeled tile NT-1 (base=65536): no staging
  {
    const unsigned base = 65536u;
    PH_BAR();
    RD4(aFB, base + 4096, offA);
    WAITL(4);
    MFMA16(0, aFA, bF0);

    PH_BAR();
    RD4(aFA, base + 32768, offA);
    RD4(bF1, base + 49152, offB);
    WAITL(8);
    MFMA16(4, aFB, bF0);

    PH_BAR();
    RD4(aFB, base + 32768 + 4096, offA);
    WAITL(4);
    MFMA16(0, aFA, bF1);

    PH_BAR();
    WAITL(0);
    MFMA16(4, aFB, bF1);
  }
#undef STG
#undef RD4
#undef PH_BAR
#undef WAITL
#undef WAITV
#undef MFMA16

  // C/D layout col=lane&15, row=(lane>>4)*4+reg  [measured m89/m91]
  const int col0 = blockN + wn * 64 + (lane & 15);
  const int row0 = blockM + wm * 128 + (lane >> 4) * 4;
#pragma unroll
  for (int i = 0; i < 8; ++i)
#pragma unroll
    for (int j = 0; j < 4; ++j) {
      float* op = out + (size_t)(row0 + i * 16) * OUT_F + col0 + j * 16;
#pragma unroll
      for (int rr = 0; rr < 4; ++rr) op[(size_t)rr * OUT_F] = acc[i][j][rr];
    }
}

// ================================================================ FALLBACK
// fp32 VALU GEMM out = x @ W^T (64x64 tile), then out += (x V s) U^T.
__global__ __launch_bounds__(256)
void fb_gemm(const float* __restrict__ x, const float* __restrict__ W,
             float* __restrict__ out) {
  __shared__ float xs[64][17];
  __shared__ float wsm[64][17];
  const int mt = blockIdx.x >> 6;
  const int ntile = blockIdx.x & 63;
  const int bM = mt * 64, bN = ntile * 64;
  const int t = threadIdx.x;
  const int lr = t >> 2, lc = (t & 3) * 4;
  const int tm = t >> 4, tn = t & 15;

  float acc[4][4];
#pragma unroll
  for (int i = 0; i < 4; ++i)
#pragma unroll
    for (int j = 0; j < 4; ++j) acc[i][j] = 0.f;

  for (int kk = 0; kk < IN_F; kk += 16) {
    float4 xa = *(const float4*)(x + (size_t)(bM + lr) * IN_F + kk + lc);
    float4 wa = *(const float4*)(W + (size_t)(bN + lr) * IN_F + kk + lc);
    xs[lr][lc + 0] = xa.x; xs[lr][lc + 1] = xa.y;
    xs[lr][lc + 2] = xa.z; xs[lr][lc + 3] = xa.w;
    wsm[lr][lc + 0] = wa.x; wsm[lr][lc + 1] = wa.y;
    wsm[lr][lc + 2] = wa.z; wsm[lr][lc + 3] = wa.w;
    __syncthreads();
#pragma unroll
    for (int k = 0; k < 16; ++k) {
      float a[4], b[4];
#pragma unroll
      for (int i = 0; i < 4; ++i) a[i] = xs[tm * 4 + i][k];
#pragma unroll
      for (int j = 0; j < 4; ++j) b[j] = wsm[tn * 4 + j][k];
#pragma unroll
      for (int i = 0; i < 4; ++i)
#pragma unroll
        for (int j = 0; j < 4; ++j) acc[i][j] += a[i] * b[j];
    }
    __syncthreads();
  }
#pragma unroll
  for (int i = 0; i < 4; ++i)
#pragma unroll
    for (int j = 0; j < 4; ++j)
      out[(size_t)(bM + tm * 4 + i) * OUT_F + bN + tn * 4 + j] = acc[i][j];
}

__global__ void fb_xv(const float* __restrict__ x, const float* __restrict__ V,
                      const float* __restrict__ S, float* __restrict__ xv) {
  int m = blockIdx.x * 4 + (threadIdx.x >> 6);
  int lane = threadIdx.x & 63;
  float a[RANK];
#pragma unroll
  for (int r = 0; r < RANK; ++r) a[r] = 0.f;
  for (int k = lane; k < IN_F; k += 64) {
    float xe = x[(size_t)m * IN_F + k];
    const float4* vp = (const float4*)(V + (size_t)k * RANK);
#pragma unroll
    for (int q = 0; q < 4; ++q) {
      float4 vv = vp[q];
      a[q * 4 + 0] += xe * vv.x; a[q * 4 + 1] += xe * vv.y;
      a[q * 4 + 2] += xe * vv.z; a[q * 4 + 3] += xe * vv.w;
    }
  }
#pragma unroll
  for (int r = 0; r < RANK; ++r)
    for (int off = 32; off; off >>= 1) a[r] += __shfl_down(a[r], off);
  if (lane == 0) {
#pragma unroll
    for (int r = 0; r < RANK; ++r) xv[(size_t)m * RANK + r] = a[r] * S[r];
  }
}

__global__ void fb_add(const float* __restrict__ xv, const float* __restrict__ U,
                       float* __restrict__ out) {
  size_t t = (size_t)blockIdx.x * 256 + threadIdx.x;
  int m = (int)(t >> 12), o = (int)(t & 4095);
  const float* xr = xv + (size_t)m * RANK;
  const float* ur = U + (size_t)o * RANK;
  float d = 0.f;
#pragma unroll
  for (int r = 0; r < RANK; ++r) d += xr[r] * ur[r];
  out[t] += d;
}

// ---------------------------------------------------------------- launch
extern "C" void kernel_launch(void* const* d_in, const int* in_sizes, int n_in,
                              void* d_out, int out_size, void* d_ws, size_t ws_size,
                              hipStream_t stream) {
  const float* x = (const float*)d_in[0];
  const float* W = (const float*)d_in[1];
  const float* U = (const float*)d_in[2];
  const float* s = (const float*)d_in[3];
  const float* V = (const float*)d_in[4];
  float* out = (float*)d_out;

  // workspace: xh (8192*4096 f16) + wh (4096*4096 f16) = 100 MiB
  const size_t need = ((size_t)M_ROWS * IN_F + (size_t)OUT_F * IN_F) * 2;
  if (ws_size >= need) {
    _Float16* xh = (_Float16*)d_ws;
    _Float16* wh = xh + (size_t)M_ROWS * IN_F;
    prep_kernel<<<SPLIT_BLOCKS + ((IN_F / 4) * (OUT_F / 8)) / 256, 256, 0, stream>>>(
        x, xh, W, U, s, V, wh);
    gemm_kernel<<<(M_ROWS / BM) * (OUT_F / BN), 512, 0, stream>>>(xh, wh, out);
  } else {
    float* xv = (float*)d_ws;  // 8192*16 f32 = 512 KiB
    fb_gemm<<<(M_ROWS / 64) * (OUT_F / 64), 256, 0, stream>>>(x, W, out);
    fb_xv<<<M_ROWS / 4, 256, 0, stream>>>(x, V, s, xv);
    fb_add<<<(size_t)M_ROWS * OUT_F / 256, 256, 0, stream>>>(xv, U, out);
  }
}